// Round 1
// 686.694 us; speedup vs baseline: 1.1171x; 1.1171x over previous
//
#include <hip/hip_runtime.h>
#include <hip/hip_bf16.h>
#include <stdint.h>

#define NE 8
#define NTOK 8192        // B*T
#define HD 1024
#define FD 4096
#define NSLOT (NTOK * 2)
#define NSEG 16
#define SEGLEN (NSLOT / NSEG)

typedef __attribute__((ext_vector_type(4))) float floatx4;
typedef __attribute__((ext_vector_type(8))) __bf16 bf16x8;
typedef __attribute__((ext_vector_type(8))) unsigned short ushortx8;

__device__ __forceinline__ unsigned short f2bf(float f) {
    union { float f; unsigned u; } v; v.f = f;
    unsigned r = v.u + 0x7FFFu + ((v.u >> 16) & 1u);   // RNE
    return (unsigned short)(r >> 16);
}

__device__ __forceinline__ void gload_lds16(const unsigned short* g, unsigned short* l) {
    __builtin_amdgcn_global_load_lds(
        (const __attribute__((address_space(1))) void*)g,
        (__attribute__((address_space(3))) void*)l,
        16, 0, 0);
}

// ------------- transpose + cast: w[e][r][c] (fp32) -> wt[e][c][r] (bf16) -------------
__global__ void transpose_cast_kernel(const float* __restrict__ w, unsigned short* __restrict__ wt,
                                      int rows, int cols) {
    __shared__ unsigned short tile[64][66];
    int e = blockIdx.z;
    int r0 = blockIdx.y * 64;
    int c0 = blockIdx.x * 64;
    const float* ws = w + (size_t)e * rows * cols;
    unsigned short* wd = wt + (size_t)e * rows * cols;
    int tid = threadIdx.x;   // 256
#pragma unroll
    for (int j = 0; j < 4; j++) {
        int idx = j * 256 + tid;
        int r = idx >> 4;
        int c4 = (idx & 15) * 4;
        float4 v = *(const float4*)(ws + (size_t)(r0 + r) * cols + c0 + c4);
        ushort2 lo, hi;
        lo.x = f2bf(v.x); lo.y = f2bf(v.y);
        hi.x = f2bf(v.z); hi.y = f2bf(v.w);
        *(ushort2*)&tile[r][c4]     = lo;
        *(ushort2*)&tile[r][c4 + 2] = hi;
    }
    __syncthreads();
#pragma unroll
    for (int j = 0; j < 2; j++) {
        int idx = j * 256 + tid;
        int c = idx >> 3;
        int r8 = (idx & 7) * 8;
        ushortx8 o;
#pragma unroll
        for (int k = 0; k < 8; k++) o[k] = tile[r8 + k][c];
        *(ushortx8*)(wd + (size_t)(c0 + c) * rows + r0 + r8) = o;
    }
}

// -------- router phase A: logits, top-2 softmax, eid/wts per slot, x->bf16 cast --------
__global__ void router_kernel(const float* __restrict__ x, const float* __restrict__ gw,
                              float* __restrict__ logits, int* __restrict__ eid,
                              float* __restrict__ wts, unsigned short* __restrict__ xb) {
    int lane = threadIdx.x & 63;
    int t = blockIdx.x * 4 + (threadIdx.x >> 6);   // one wave per token
    const float* xr = x + (size_t)t * HD;
    unsigned short* xbr = xb + (size_t)t * HD;
    float a0=0,a1=0,a2=0,a3=0,a4=0,a5=0,a6=0,a7=0;
    for (int c = lane; c < HD; c += 64) {
        float xv = xr[c];
        xbr[c] = f2bf(xv);
        const float4* g = (const float4*)(gw + (size_t)c * NE);
        float4 g0 = g[0], g1 = g[1];
        a0 += xv * g0.x; a1 += xv * g0.y; a2 += xv * g0.z; a3 += xv * g0.w;
        a4 += xv * g1.x; a5 += xv * g1.y; a6 += xv * g1.z; a7 += xv * g1.w;
    }
#pragma unroll
    for (int off = 32; off > 0; off >>= 1) {
        a0 += __shfl_xor(a0, off); a1 += __shfl_xor(a1, off);
        a2 += __shfl_xor(a2, off); a3 += __shfl_xor(a3, off);
        a4 += __shfl_xor(a4, off); a5 += __shfl_xor(a5, off);
        a6 += __shfl_xor(a6, off); a7 += __shfl_xor(a7, off);
    }
    if (lane == 0) {
        float l[8] = {a0,a1,a2,a3,a4,a5,a6,a7};
        float4 s0 = make_float4(a0,a1,a2,a3);
        float4 s1 = make_float4(a4,a5,a6,a7);
        ((float4*)(logits + (size_t)t * NE))[0] = s0;
        ((float4*)(logits + (size_t)t * NE))[1] = s1;
        int e0 = 0; float v0 = l[0];
#pragma unroll
        for (int e = 1; e < 8; e++) if (l[e] > v0) { v0 = l[e]; e0 = e; }
        int e1 = -1; float v1 = -3.4e38f;
#pragma unroll
        for (int e = 0; e < 8; e++) if (e != e0 && l[e] > v1) { v1 = l[e]; e1 = e; }
        float ex = __expf(v1 - v0);
        float dn = 1.f + ex;
        wts[2*t]   = 1.f / dn;
        wts[2*t+1] = ex / dn;
        eid[2*t]   = e0;
        eid[2*t+1] = e1;
    }
}

// -------- router phase B: hierarchical perm build (cuts the 256-step serial scan 16x) --------
__global__ void count_seg_kernel(const int* __restrict__ eid, int* __restrict__ segcnt) {
    int e = blockIdx.x >> 4;
    int seg = blockIdx.x & 15;
    int lane = threadIdx.x;       // 64
    int base = seg * SEGLEN;
    int cnt = 0;
    for (int i0 = 0; i0 < SEGLEN; i0 += 64) {
        bool mt = (eid[base + i0 + lane] == e);
        cnt += __popcll(__ballot(mt));
    }
    if (lane == 0) segcnt[blockIdx.x] = cnt;
}

__global__ void fill_perm_kernel(const int* __restrict__ eid, const int* __restrict__ segcnt,
                                 int* __restrict__ perm, int* __restrict__ counts) {
    int e = blockIdx.x >> 4;
    int seg = blockIdx.x & 15;
    int lane = threadIdx.x;       // 64
    int base = 0;
#pragma unroll
    for (int s2 = 0; s2 < NSEG; s2++)
        if (s2 < seg) base += segcnt[(e << 4) + s2];
    int* permE = perm + e * NTOK;
    int g0 = seg * SEGLEN;
    for (int i0 = 0; i0 < SEGLEN; i0 += 64) {
        int s = g0 + i0 + lane;
        bool mt = (eid[s] == e);
        unsigned long long mask = __ballot(mt);
        int pre = __popcll(mask & ((1ULL << lane) - 1ULL));
        if (mt) permE[base + pre] = s;
        base += __popcll(mask);
    }
    if (lane == 0 && seg == NSEG - 1) counts[e] = base;
}

// ---------------- gathered GEMM: expert->XCD swizzle + counted-vmcnt dbuf pipeline ----------------
// C[M x NTOT] = gather(A)[M x KTOT] * Bt[e]^T, Bt stored [NTOT x KTOT] (B^T).
// G1: A row = xb[slot>>1], epilogue relu->bf16 into h[slot].
// !G1: A row = h[slot], epilogue atomicAdd(out[slot>>1], w[slot]*acc).
template<int KTOT, int NTOT, bool G1>
__global__ __launch_bounds__(256, 2)
void moe_gemm(const unsigned short* __restrict__ A,
              const unsigned short* __restrict__ Bt,
              unsigned short* __restrict__ Hout,
              float* __restrict__ Out,
              const int* __restrict__ counts,
              const int* __restrict__ perm,
              const float* __restrict__ wts) {
    // Swizzle: bid%8 == XCD id (dispatch round-robins consecutive ids across 8 XCDs).
    // XCD k owns expert k entirely (counts are ~balanced). Within an expert, blocks are
    // ordered in 8x8 (mtile,ntile) supertiles: A-slab + B-slab ~4 MiB -> fits per-XCD L2.
    constexpr int GX = NTOT / 128;   // n-tiles: 32 (G1) or 8 (!G1)
    constexpr int SN = GX / 8;       // n-supergroups: 4 or 1
    int bid = blockIdx.y * GX + blockIdx.x;
    int e = bid & 7;
    int i = bid >> 3;                // [0, GX*64)
    int st = i >> 6, pos = i & 63;
    int mg = st / SN, ng = st % SN;  // mg-major: consecutive supertiles reuse the A slab
    int mtile = mg * 8 + (pos >> 3);
    int n0 = (ng * 8 + (pos & 7)) * 128;

    int cnt = counts[e];
    if (mtile * 128 >= cnt) return;

    __shared__ unsigned short lds[2 * 16384];   // 64 KiB: [buf][A 8K | B 8K] elems

    int tid = threadIdx.x;
    int lane = tid & 63;
    int wv = tid >> 6;
    const int* permE = perm + e * NTOK + mtile * 128;

    // staging row pointers: thread handles rows r_it = it*32 + (tid>>3)
    const unsigned short* aRow[4];
    const unsigned short* bRow[4];
#pragma unroll
    for (int it = 0; it < 4; it++) {
        int r = it * 32 + (tid >> 3);
        int s = (mtile * 128 + r < cnt) ? permE[r] : permE[0];   // clamp to a valid row
        size_t arow = G1 ? (size_t)(s >> 1) : (size_t)s;
        aRow[it] = A + arow * KTOT;
        bRow[it] = Bt + ((size_t)e * NTOT + n0 + r) * KTOT;
    }
    // XOR swizzle: logical k-chunk j of row r lives at physical chunk j^(r&7).
    int koff = ((tid & 7) ^ ((tid >> 3) & 7)) * 8;   // elements
    int wbase = (tid & 192) * 8;                     // wave-uniform LDS chunk base (elems)

    floatx4 acc[4][4];
    floatx4 zero = {0.f, 0.f, 0.f, 0.f};
#pragma unroll
    for (int a = 0; a < 4; a++)
#pragma unroll
        for (int b = 0; b < 4; b++) acc[a][b] = zero;

    int m = lane & 15, quad = lane >> 4;
    int rA = (wv >> 1) * 64 + m;     // + mi*16
    int rB = (wv & 1) * 64 + m;      // + ni*16
    int xs = m & 7;                  // fragment-read swizzle (row&7 == m&7)

    constexpr int NK = KTOT / 64;

    auto stage = [&](int buf, int k0) {
        unsigned short* la = &lds[buf * 16384];
        unsigned short* lb = la + 8192;
#pragma unroll
        for (int it = 0; it < 4; it++)
            gload_lds16(aRow[it] + k0 + koff, la + it * 2048 + wbase);
#pragma unroll
        for (int it = 0; it < 4; it++)
            gload_lds16(bRow[it] + k0 + koff, lb + it * 2048 + wbase);
    };

    stage(0, 0);                         // prologue: tile 0 in flight (8 loads/thread)
    int cur = 0;
#pragma unroll 2
    for (int kt = 0; kt < NK; kt++) {
        if (kt + 1 < NK) {
            stage(cur ^ 1, (kt + 1) * 64);                 // prefetch next tile (8 more loads)
            asm volatile("s_waitcnt vmcnt(8)" ::: "memory");  // wait ONLY tile kt's 8
        } else {
            asm volatile("s_waitcnt vmcnt(0)" ::: "memory");
        }
        __builtin_amdgcn_sched_barrier(0);
        __builtin_amdgcn_s_barrier();                      // raw: no vmcnt(0) drain
        __builtin_amdgcn_sched_barrier(0);

        const unsigned short* la = &lds[cur * 16384];
        const unsigned short* lb = la + 8192;
#pragma unroll
        for (int kk = 0; kk < 2; kk++) {
            bf16x8 af[4], bfr[4];
#pragma unroll
            for (int mi = 0; mi < 4; mi++)
                af[mi] = *(const bf16x8*)(la + (((rA + mi * 16) * 8 + ((kk * 4 + quad) ^ xs)) * 8));
#pragma unroll
            for (int ni = 0; ni < 4; ni++)
                bfr[ni] = *(const bf16x8*)(lb + (((rB + ni * 16) * 8 + ((kk * 4 + quad) ^ xs)) * 8));
            __builtin_amdgcn_s_setprio(1);
#pragma unroll
            for (int mi = 0; mi < 4; mi++)
#pragma unroll
                for (int ni = 0; ni < 4; ni++)
                    acc[mi][ni] = __builtin_amdgcn_mfma_f32_16x16x32_bf16(af[mi], bfr[ni], acc[mi][ni], 0, 0, 0);
            __builtin_amdgcn_s_setprio(0);
        }
        // all my LDS reads done before anyone overwrites this buffer next iteration
        asm volatile("s_waitcnt lgkmcnt(0)" ::: "memory");
        __builtin_amdgcn_sched_barrier(0);
        __builtin_amdgcn_s_barrier();
        __builtin_amdgcn_sched_barrier(0);
        cur ^= 1;
    }

    // epilogue: C/D layout col = lane&15, row = quad*4 + reg
    int colb = (wv & 1) * 64 + m;          // + ni*16
    int rb = (wv >> 1) * 64 + quad * 4;    // + mi*16 + reg
#pragma unroll
    for (int mi = 0; mi < 4; mi++) {
#pragma unroll
        for (int reg = 0; reg < 4; reg++) {
            int rl = rb + mi * 16 + reg;
            if (mtile * 128 + rl >= cnt) continue;
            int s = permE[rl];             // 512 B segment, L2-hot
            if (G1) {
                unsigned short* hr = Hout + (size_t)s * NTOT + n0 + colb;
#pragma unroll
                for (int ni = 0; ni < 4; ni++) {
                    float v = acc[mi][ni][reg];
                    hr[ni * 16] = f2bf(v > 0.f ? v : 0.f);
                }
            } else {
                float w = wts[s];
                float* orow = Out + (size_t)(s >> 1) * NTOT + n0 + colb;
#pragma unroll
                for (int ni = 0; ni < 4; ni++)
                    atomicAdd(&orow[ni * 16], w * acc[mi][ni][reg]);
            }
        }
    }
}

extern "C" void kernel_launch(void* const* d_in, const int* in_sizes, int n_in,
                              void* d_out, int out_size, void* d_ws, size_t ws_size,
                              hipStream_t stream) {
    (void)in_sizes; (void)n_in; (void)out_size;
    const float* x  = (const float*)d_in[0];
    const float* gw = (const float*)d_in[1];
    const float* w1 = (const float*)d_in[2];
    const float* w2 = (const float*)d_in[3];
    float* out = (float*)d_out;
    float* logits = out + (size_t)NTOK * HD;

    char* ws = (char*)d_ws;
    int*   counts = (int*)ws;                                   // 256 B
    int*   perm   = (int*)(ws + 256);                           // 8*8192*4 = 256 KiB
    float* wts    = (float*)(ws + 256 + 262144);                // 64 KiB
    int*   eid    = (int*)(ws + 256 + 262144 + 65536);          // 64 KiB
    int*   segcnt = (int*)(ws + 393472);                        // 512 B (in the pre-xb gap)
    unsigned short* xb    = (unsigned short*)(ws + 458752);                // 16 MiB
    unsigned short* wtbuf = xb + (size_t)NTOK * HD;                        // 64 MiB (w1t, then w2t)
    unsigned short* h     = wtbuf + (size_t)NE * HD * FD;                  // 128 MiB
    size_t needed = 458752 + (size_t)NTOK*HD*2 + (size_t)NE*HD*FD*2 + (size_t)NSLOT*FD*2;
    if (ws_size < needed) return;   // workspace too small — cannot run

    hipMemsetAsync(out, 0, (size_t)NTOK * HD * sizeof(float), stream);

    // w1: [E][H][F] -> w1t [E][F][H]  (rows=H, cols=F)
    transpose_cast_kernel<<<dim3(FD / 64, HD / 64, NE), 256, 0, stream>>>(w1, wtbuf, HD, FD);
    router_kernel<<<NTOK / 4, 256, 0, stream>>>(x, gw, logits, eid, wts, xb);
    count_seg_kernel<<<NE * NSEG, 64, 0, stream>>>(eid, segcnt);
    fill_perm_kernel<<<NE * NSEG, 64, 0, stream>>>(eid, segcnt, perm, counts);
    // h[s] = relu(xb[token] @ w1[e]) : K=1024, N=4096
    moe_gemm<HD, FD, true><<<dim3(FD / 128, NE * 64), 256, 0, stream>>>(
        xb, wtbuf, h, nullptr, counts, perm, wts);
    // w2: [E][F][H] -> w2t [E][H][F] (reuse wtbuf; stream order serializes after gemm1)
    transpose_cast_kernel<<<dim3(HD / 64, FD / 64, NE), 256, 0, stream>>>(w2, wtbuf, FD, HD);
    // out[t] += w[s] * (h[s] @ w2[e]) : K=4096, N=1024
    moe_gemm<FD, HD, false><<<dim3(HD / 128, NE * 64), 256, 0, stream>>>(
        h, wtbuf, nullptr, out, counts, perm, wts);
}